// Round 2
// baseline (455.563 us; speedup 1.0000x reference)
//
#include <hip/hip_runtime.h>
#include <hip/hip_bf16.h>

typedef unsigned int uint;

#define NPTS 4096
#define BLK  256
#define KNN  32
#define KSUP 8

// ---------------- Pass 1: kNN + PCA normal per point ----------------
__global__ __launch_bounds__(256) void knn_normal_kernel(
        const float* __restrict__ xyz,   // [B][N][3]
        float* __restrict__ normals,     // [B][N][3]
        int*   __restrict__ idx8)        // [B][N][8]
{
    const int pid = blockIdx.x;          // b*N + n
    const int b   = pid >> 12;
    const int n   = pid & (NPTS - 1);
    const int tid = threadIdx.x;
    const float* base = xyz + (size_t)b * NPTS * 3;

    __shared__ uint keys[NPTS];
    __shared__ uint hist[NPTS];
    __shared__ uint psum[BLK];
    __shared__ uint s_bin;
    __shared__ uint coll_cnt;
    __shared__ uint ckey[512];
    __shared__ int  cidx[512];
    __shared__ int  sel[KNN];

    const float xn0 = base[n*3+0], xn1 = base[n*3+1], xn2 = base[n*3+2];
    const float sqn = xn0*xn0 + xn1*xn1 + xn2*xn2;

    for (int i = tid; i < NPTS; i += BLK) hist[i] = 0;
    __syncthreads();

    // distances -> monotone uint keys + histogram of top-12 bits
    for (int m = tid; m < NPTS; m += BLK) {
        float x0 = base[m*3+0], x1 = base[m*3+1], x2 = base[m*3+2];
        float sqm = x0*x0 + x1*x1 + x2*x2;
        float d = sqn + sqm - 2.0f*(xn0*x0 + xn1*x1 + xn2*x2);
        uint u = __float_as_uint(d);
        u ^= (u & 0x80000000u) ? 0xFFFFFFFFu : 0x80000000u;
        keys[m] = u;
        atomicAdd(&hist[u >> 20], 1u);
    }
    __syncthreads();

    // partial sums of 16-bin chunks
    {
        uint s = 0;
        #pragma unroll
        for (int j = 0; j < 16; ++j) s += hist[tid*16 + j];
        psum[tid] = s;
    }
    __syncthreads();

    if (tid == 0) {
        uint cum = 0; int t = 0;
        while (t < BLK && cum + psum[t] < KNN) { cum += psum[t]; ++t; }
        int bin = t * 16;
        for (;;) { cum += hist[bin]; if (cum >= KNN) break; ++bin; }
        s_bin = (uint)bin;
        coll_cnt = 0;
    }
    __syncthreads();
    const uint bmax = s_bin;

    // collect all candidates with bin <= bmax  (superset of the true top-32)
    for (int m = tid; m < NPTS; m += BLK) {
        uint u = keys[m];
        if ((u >> 20) <= bmax) {
            uint p = atomicAdd(&coll_cnt, 1u);
            if (p < 512u) { ckey[p] = u; cidx[p] = m; }
        }
    }
    __syncthreads();
    const int M = (int)min(coll_cnt, 512u);

    // exact stable rank selection (key asc, index asc on ties) -> sel[0..31]
    for (int i = tid; i < M; i += BLK) {
        uint uk = ckey[i]; int ui = cidx[i];
        int r = 0;
        for (int j = 0; j < M; ++j) {
            uint vk = ckey[j];
            r += (vk < uk || (vk == uk && cidx[j] < ui)) ? 1 : 0;
        }
        if (r < KNN) sel[r] = ui;
    }
    __syncthreads();

    // lanes 0..31 of wave 0: gather neighbors, mean, covariance
    if (tid < 32) {
        int j = sel[tid];
        float q0 = base[j*3+0], q1 = base[j*3+1], q2 = base[j*3+2];

        float s0 = q0, s1 = q1, s2 = q2;
        #pragma unroll
        for (int ml = 1; ml < 32; ml <<= 1) {
            s0 += __shfl_xor(s0, ml, 32);
            s1 += __shfl_xor(s1, ml, 32);
            s2 += __shfl_xor(s2, ml, 32);
        }
        const float c0 = s0 * (1.0f/32.0f), c1 = s1 * (1.0f/32.0f), c2 = s2 * (1.0f/32.0f);
        const float X0 = q0 - c0, X1 = q1 - c1, X2 = q2 - c2;
        float xx = X0*X0, xy = X0*X1, xz = X0*X2, yy = X1*X1, yz = X1*X2, zz = X2*X2;
        #pragma unroll
        for (int ml = 1; ml < 32; ml <<= 1) {
            xx += __shfl_xor(xx, ml, 32);
            xy += __shfl_xor(xy, ml, 32);
            xz += __shfl_xor(xz, ml, 32);
            yy += __shfl_xor(yy, ml, 32);
            yz += __shfl_xor(yz, ml, 32);
            zz += __shfl_xor(zz, ml, 32);
        }
        // S = sum_k (nbr_k - x_n)
        const float S0 = s0 - 32.0f*xn0, S1 = s1 - 32.0f*xn1, S2 = s2 - 32.0f*xn2;

        if (tid == 0) {
            // 3x3 symmetric Jacobi eigensolve in double (register-resident)
            double A00 = xx, A01 = xy, A02 = xz, A11 = yy, A12 = yz, A22 = zz;
            double V00=1, V01=0, V02=0, V10=0, V11=1, V12=0, V20=0, V21=0, V22=1;

            #pragma unroll
            for (int sweep = 0; sweep < 8; ++sweep) {
                // rotation (0,1)
                {
                    double apq = A01;
                    if (fabs(apq) > 1e-300) {
                        double th = (A11 - A00) / (2.0*apq);
                        double t  = (th >= 0.0 ? 1.0 : -1.0) / (fabs(th) + sqrt(th*th + 1.0));
                        double c  = 1.0/sqrt(t*t + 1.0), s = t*c;
                        double a00 = c*c*A00 - 2.0*s*c*A01 + s*s*A11;
                        double a11 = s*s*A00 + 2.0*s*c*A01 + c*c*A11;
                        double a02 = c*A02 - s*A12;
                        double a12 = s*A02 + c*A12;
                        A00 = a00; A11 = a11; A01 = 0.0; A02 = a02; A12 = a12;
                        double v0, v1;
                        v0 = V00; v1 = V01; V00 = c*v0 - s*v1; V01 = s*v0 + c*v1;
                        v0 = V10; v1 = V11; V10 = c*v0 - s*v1; V11 = s*v0 + c*v1;
                        v0 = V20; v1 = V21; V20 = c*v0 - s*v1; V21 = s*v0 + c*v1;
                    }
                }
                // rotation (0,2)
                {
                    double apq = A02;
                    if (fabs(apq) > 1e-300) {
                        double th = (A22 - A00) / (2.0*apq);
                        double t  = (th >= 0.0 ? 1.0 : -1.0) / (fabs(th) + sqrt(th*th + 1.0));
                        double c  = 1.0/sqrt(t*t + 1.0), s = t*c;
                        double a00 = c*c*A00 - 2.0*s*c*A02 + s*s*A22;
                        double a22 = s*s*A00 + 2.0*s*c*A02 + c*c*A22;
                        double a01 = c*A01 - s*A12;
                        double a12 = s*A01 + c*A12;
                        A00 = a00; A22 = a22; A02 = 0.0; A01 = a01; A12 = a12;
                        double v0, v1;
                        v0 = V00; v1 = V02; V00 = c*v0 - s*v1; V02 = s*v0 + c*v1;
                        v0 = V10; v1 = V12; V10 = c*v0 - s*v1; V12 = s*v0 + c*v1;
                        v0 = V20; v1 = V22; V20 = c*v0 - s*v1; V22 = s*v0 + c*v1;
                    }
                }
                // rotation (1,2)
                {
                    double apq = A12;
                    if (fabs(apq) > 1e-300) {
                        double th = (A22 - A11) / (2.0*apq);
                        double t  = (th >= 0.0 ? 1.0 : -1.0) / (fabs(th) + sqrt(th*th + 1.0));
                        double c  = 1.0/sqrt(t*t + 1.0), s = t*c;
                        double a11 = c*c*A11 - 2.0*s*c*A12 + s*s*A22;
                        double a22 = s*s*A11 + 2.0*s*c*A12 + c*c*A22;
                        double a01 = c*A01 - s*A02;
                        double a02 = s*A01 + c*A02;
                        A11 = a11; A22 = a22; A12 = 0.0; A01 = a01; A02 = a02;
                        double v0, v1;
                        v0 = V01; v1 = V02; V01 = c*v0 - s*v1; V02 = s*v0 + c*v1;
                        v0 = V11; v1 = V12; V11 = c*v0 - s*v1; V12 = s*v0 + c*v1;
                        v0 = V21; v1 = V22; V21 = c*v0 - s*v1; V22 = s*v0 + c*v1;
                    }
                }
            }

            // pick column of smallest eigenvalue
            double e0 = A00, e1 = A11, e2 = A22;
            double v0, v1, v2;
            if (e0 <= e1 && e0 <= e2)      { v0 = V00; v1 = V10; v2 = V20; }
            else if (e1 <= e0 && e1 <= e2) { v0 = V01; v1 = V11; v2 = V21; }
            else                           { v0 = V02; v1 = V12; v2 = V22; }
            double nrm = sqrt(v0*v0 + v1*v1 + v2*v2);
            if (nrm > 0.0) { v0 /= nrm; v1 /= nrm; v2 /= nrm; }

            float f0 = (float)v0, f1 = (float)v1, f2 = (float)v2;
            float proj = f0*S0 + f1*S1 + f2*S2;
            if (proj < 0.0f) { f0 = -f0; f1 = -f1; f2 = -f2; }
            normals[(size_t)pid*3+0] = f0;
            normals[(size_t)pid*3+1] = f1;
            normals[(size_t)pid*3+2] = f2;
        }
    }
    if (tid < KSUP) idx8[(size_t)pid*KSUP + tid] = sel[tid];
}

// ---------------- Pass 2: penalty std + batch mean ----------------
__global__ __launch_bounds__(256) void penalty_kernel(
        const float* __restrict__ normals,
        const int*   __restrict__ idx8,
        float*       __restrict__ out)
{
    const int pid = blockIdx.x * BLK + threadIdx.x;   // < B*N
    const int b   = pid >> 12;
    const int* my = idx8 + (size_t)pid * KSUP;
    const float* nb_base = normals + (size_t)b * NPTS * 3;

    const int i0 = my[0];
    const float a0 = nb_base[i0*3+0], a1 = nb_base[i0*3+1], a2 = nb_base[i0*3+2];
    const float na = fmaxf(sqrtf(a0*a0 + a1*a1 + a2*a2), 1e-6f);

    float p[KSUP];
    float sum = 0.0f;
    #pragma unroll
    for (int k = 0; k < KSUP; ++k) {
        int ik = my[k];
        float b0 = nb_base[ik*3+0], b1 = nb_base[ik*3+1], b2 = nb_base[ik*3+2];
        float nbn = fmaxf(sqrtf(b0*b0 + b1*b1 + b2*b2), 1e-6f);
        float cosv = (a0*b0 + a1*b1 + a2*b2) / (na * nbn);
        p[k] = 1.0f - cosv;
        sum += p[k];
    }
    const float mean = sum * (1.0f / 8.0f);
    float var = 0.0f;
    #pragma unroll
    for (int k = 0; k < KSUP; ++k) { float dv = p[k] - mean; var += dv * dv; }
    float v = sqrtf(var * (1.0f / 7.0f)) * (1.0f / 4096.0f);

    // reduce 256 threads (same b within a block: 4096 % 256 == 0)
    #pragma unroll
    for (int ml = 1; ml < 64; ml <<= 1) v += __shfl_xor(v, ml, 64);
    __shared__ float red[4];
    if ((threadIdx.x & 63) == 0) red[threadIdx.x >> 6] = v;
    __syncthreads();
    if (threadIdx.x == 0) {
        atomicAdd(&out[b], red[0] + red[1] + red[2] + red[3]);
    }
}

extern "C" void kernel_launch(void* const* d_in, const int* in_sizes, int n_in,
                              void* d_out, int out_size, void* d_ws, size_t ws_size,
                              hipStream_t stream) {
    const float* xyz = (const float*)d_in[0];
    float* out = (float*)d_out;

    const int B = in_sizes[0] / (NPTS * 3);   // 4

    float* normals = (float*)d_ws;
    int*   idx8    = (int*)((char*)d_ws + (size_t)B * NPTS * 3 * sizeof(float));

    hipMemsetAsync(d_out, 0, (size_t)out_size * sizeof(float), stream);

    hipLaunchKernelGGL(knn_normal_kernel, dim3(B * NPTS), dim3(BLK), 0, stream,
                       xyz, normals, idx8);
    hipLaunchKernelGGL(penalty_kernel, dim3((B * NPTS) / BLK), dim3(BLK), 0, stream,
                       normals, idx8, out);
}

// Round 3
// 224.947 us; speedup vs baseline: 2.0252x; 2.0252x over previous
//
#include <hip/hip_runtime.h>
#include <hip/hip_bf16.h>

typedef unsigned int uint;

#define NPTS 4096
#define BLK  256
#define KNN  32
#define KSUP 8
#define NBIN 1024
#define BSHIFT 22
#define MAXC 512

// ---------------- Pass 0: pack xyz -> float4 {x,y,z,|x|^2} ----------------
__global__ __launch_bounds__(256) void pack_kernel(
        const float* __restrict__ xyz, float4* __restrict__ pts4, int total)
{
    int i = blockIdx.x * BLK + threadIdx.x;
    if (i < total) {
        float x = xyz[i*3+0], y = xyz[i*3+1], z = xyz[i*3+2];
        pts4[i] = make_float4(x, y, z, x*x + y*y + z*z);
    }
}

__device__ __forceinline__ uint fkey(float d) {
    uint u = __float_as_uint(d);
    return u ^ ((u & 0x80000000u) ? 0xFFFFFFFFu : 0x80000000u);
}

// ---------------- Pass 1: kNN + PCA normal per point ----------------
__global__ __launch_bounds__(256) void knn_normal_kernel(
        const float4* __restrict__ pts4,  // [B][N] {x,y,z,sq}
        float* __restrict__ normals,      // [B][N][3]
        int*   __restrict__ idx8)         // [B][N][8]
{
    const int pid = blockIdx.x;           // b*N + n
    const int b   = pid >> 12;
    const int n   = pid & (NPTS - 1);
    const int tid = threadIdx.x;
    const float4* P = pts4 + (size_t)b * NPTS;

    __shared__ uint hist[NBIN];
    __shared__ uint s_bin;
    __shared__ uint coll_cnt;
    __shared__ uint ckey[MAXC];
    __shared__ int  cidx[MAXC];
    __shared__ int  sel[KNN];

    const float4 q = P[n];
    const float qx = q.x, qy = q.y, qz = q.z, sqn = q.w;

    #pragma unroll
    for (int i = 0; i < NBIN / BLK; ++i) hist[tid + i * BLK] = 0;
    if (tid == 0) coll_cnt = 0;
    __syncthreads();

    // ---- histogram of top-10 key bits ----
    #pragma unroll 4
    for (int m = tid; m < NPTS; m += BLK) {
        float4 p = P[m];
        float d = sqn + p.w - 2.0f * (qx * p.x + qy * p.y + qz * p.z);
        atomicAdd(&hist[fkey(d) >> BSHIFT], 1u);
    }
    __syncthreads();

    // ---- wave 0: parallel threshold-bin find (prefix scan + ballot crossing) ----
    if (tid < 64) {
        const uint4* h4 = (const uint4*)hist;
        uint4 h0 = h4[tid*4+0], h1 = h4[tid*4+1], h2 = h4[tid*4+2], h3 = h4[tid*4+3];
        uint s = h0.x+h0.y+h0.z+h0.w + h1.x+h1.y+h1.z+h1.w
               + h2.x+h2.y+h2.z+h2.w + h3.x+h3.y+h3.z+h3.w;
        uint t = s;
        #pragma unroll
        for (int off = 1; off < 64; off <<= 1) {
            uint u = __shfl_up(t, off, 64);
            if (tid >= off) t += u;
        }
        uint ex = t - s;                       // exclusive prefix over lanes
        if (ex < KNN && ex + s >= KNN) {       // exactly one crossing lane
            uint cum = ex, binoff = 0;
            cum += h0.x; binoff += (cum < KNN); cum += h0.y; binoff += (cum < KNN);
            cum += h0.z; binoff += (cum < KNN); cum += h0.w; binoff += (cum < KNN);
            cum += h1.x; binoff += (cum < KNN); cum += h1.y; binoff += (cum < KNN);
            cum += h1.z; binoff += (cum < KNN); cum += h1.w; binoff += (cum < KNN);
            cum += h2.x; binoff += (cum < KNN); cum += h2.y; binoff += (cum < KNN);
            cum += h2.z; binoff += (cum < KNN); cum += h2.w; binoff += (cum < KNN);
            cum += h3.x; binoff += (cum < KNN); cum += h3.y; binoff += (cum < KNN);
            cum += h3.z; binoff += (cum < KNN); cum += h3.w; binoff += (cum < KNN);
            s_bin = tid * 16u + binoff;
        }
    }
    __syncthreads();
    const uint bmax = s_bin;

    // ---- collect candidates with bin <= bmax (superset of true top-32) ----
    #pragma unroll 4
    for (int m = tid; m < NPTS; m += BLK) {
        float4 p = P[m];
        float d = sqn + p.w - 2.0f * (qx * p.x + qy * p.y + qz * p.z);
        uint u = fkey(d);
        if ((u >> BSHIFT) <= bmax) {
            uint pos = atomicAdd(&coll_cnt, 1u);
            if (pos < MAXC) { ckey[pos] = u; cidx[pos] = m; }
        }
    }
    __syncthreads();
    const int M = (int)min(coll_cnt, (uint)MAXC);

    // ---- exact stable rank selection (key asc, index asc) -> sel[0..31] ----
    for (int i = tid; i < M; i += BLK) {
        uint uk = ckey[i]; int ui = cidx[i];
        int r = 0;
        for (int j = 0; j < M; ++j) {
            uint vk = ckey[j];
            r += (vk < uk || (vk == uk && cidx[j] < ui)) ? 1 : 0;
        }
        if (r < KNN) sel[r] = ui;
    }
    __syncthreads();

    // ---- lanes 0..31: gather neighbors, mean, covariance ----
    if (tid < 32) {
        int j = sel[tid];
        float4 pj = P[j];
        float q0 = pj.x, q1 = pj.y, q2 = pj.z;

        float s0 = q0, s1 = q1, s2 = q2;
        #pragma unroll
        for (int ml = 1; ml < 32; ml <<= 1) {
            s0 += __shfl_xor(s0, ml, 32);
            s1 += __shfl_xor(s1, ml, 32);
            s2 += __shfl_xor(s2, ml, 32);
        }
        const float c0 = s0 * (1.0f/32.0f), c1 = s1 * (1.0f/32.0f), c2 = s2 * (1.0f/32.0f);
        const float X0 = q0 - c0, X1 = q1 - c1, X2 = q2 - c2;
        float xx = X0*X0, xy = X0*X1, xz = X0*X2, yy = X1*X1, yz = X1*X2, zz = X2*X2;
        #pragma unroll
        for (int ml = 1; ml < 32; ml <<= 1) {
            xx += __shfl_xor(xx, ml, 32);
            xy += __shfl_xor(xy, ml, 32);
            xz += __shfl_xor(xz, ml, 32);
            yy += __shfl_xor(yy, ml, 32);
            yz += __shfl_xor(yz, ml, 32);
            zz += __shfl_xor(zz, ml, 32);
        }
        const float S0 = s0 - 32.0f*qx, S1 = s1 - 32.0f*qy, S2 = s2 - 32.0f*qz;

        if (tid == 0) {
            // 3x3 symmetric Jacobi eigensolve in double (register-resident)
            double A00 = xx, A01 = xy, A02 = xz, A11 = yy, A12 = yz, A22 = zz;
            double V00=1, V01=0, V02=0, V10=0, V11=1, V12=0, V20=0, V21=0, V22=1;

            #pragma unroll
            for (int sweep = 0; sweep < 5; ++sweep) {
                {
                    double apq = A01;
                    if (fabs(apq) > 1e-300) {
                        double th = (A11 - A00) / (2.0*apq);
                        double t  = (th >= 0.0 ? 1.0 : -1.0) / (fabs(th) + sqrt(th*th + 1.0));
                        double c  = 1.0/sqrt(t*t + 1.0), s = t*c;
                        double a00 = c*c*A00 - 2.0*s*c*A01 + s*s*A11;
                        double a11 = s*s*A00 + 2.0*s*c*A01 + c*c*A11;
                        double a02 = c*A02 - s*A12;
                        double a12 = s*A02 + c*A12;
                        A00 = a00; A11 = a11; A01 = 0.0; A02 = a02; A12 = a12;
                        double v0, v1;
                        v0 = V00; v1 = V01; V00 = c*v0 - s*v1; V01 = s*v0 + c*v1;
                        v0 = V10; v1 = V11; V10 = c*v0 - s*v1; V11 = s*v0 + c*v1;
                        v0 = V20; v1 = V21; V20 = c*v0 - s*v1; V21 = s*v0 + c*v1;
                    }
                }
                {
                    double apq = A02;
                    if (fabs(apq) > 1e-300) {
                        double th = (A22 - A00) / (2.0*apq);
                        double t  = (th >= 0.0 ? 1.0 : -1.0) / (fabs(th) + sqrt(th*th + 1.0));
                        double c  = 1.0/sqrt(t*t + 1.0), s = t*c;
                        double a00 = c*c*A00 - 2.0*s*c*A02 + s*s*A22;
                        double a22 = s*s*A00 + 2.0*s*c*A02 + c*c*A22;
                        double a01 = c*A01 - s*A12;
                        double a12 = s*A01 + c*A12;
                        A00 = a00; A22 = a22; A02 = 0.0; A01 = a01; A12 = a12;
                        double v0, v1;
                        v0 = V00; v1 = V02; V00 = c*v0 - s*v1; V02 = s*v0 + c*v1;
                        v0 = V10; v1 = V12; V10 = c*v0 - s*v1; V12 = s*v0 + c*v1;
                        v0 = V20; v1 = V22; V20 = c*v0 - s*v1; V22 = s*v0 + c*v1;
                    }
                }
                {
                    double apq = A12;
                    if (fabs(apq) > 1e-300) {
                        double th = (A22 - A11) / (2.0*apq);
                        double t  = (th >= 0.0 ? 1.0 : -1.0) / (fabs(th) + sqrt(th*th + 1.0));
                        double c  = 1.0/sqrt(t*t + 1.0), s = t*c;
                        double a11 = c*c*A11 - 2.0*s*c*A12 + s*s*A22;
                        double a22 = s*s*A11 + 2.0*s*c*A12 + c*c*A22;
                        double a01 = c*A01 - s*A02;
                        double a02 = s*A01 + c*A02;
                        A11 = a11; A22 = a22; A12 = 0.0; A01 = a01; A02 = a02;
                        double v0, v1;
                        v0 = V01; v1 = V02; V01 = c*v0 - s*v1; V02 = s*v0 + c*v1;
                        v0 = V11; v1 = V12; V11 = c*v0 - s*v1; V12 = s*v0 + c*v1;
                        v0 = V21; v1 = V22; V21 = c*v0 - s*v1; V22 = s*v0 + c*v1;
                    }
                }
            }

            double e0 = A00, e1 = A11, e2 = A22;
            double v0, v1, v2;
            if (e0 <= e1 && e0 <= e2)      { v0 = V00; v1 = V10; v2 = V20; }
            else if (e1 <= e0 && e1 <= e2) { v0 = V01; v1 = V11; v2 = V21; }
            else                           { v0 = V02; v1 = V12; v2 = V22; }
            double nrm = sqrt(v0*v0 + v1*v1 + v2*v2);
            if (nrm > 0.0) { v0 /= nrm; v1 /= nrm; v2 /= nrm; }

            float f0 = (float)v0, f1 = (float)v1, f2 = (float)v2;
            float proj = f0*S0 + f1*S1 + f2*S2;
            if (proj < 0.0f) { f0 = -f0; f1 = -f1; f2 = -f2; }
            normals[(size_t)pid*3+0] = f0;
            normals[(size_t)pid*3+1] = f1;
            normals[(size_t)pid*3+2] = f2;
        }
    }
    if (tid < KSUP) idx8[(size_t)pid*KSUP + tid] = sel[tid];
}

// ---------------- Pass 2: penalty std + batch mean ----------------
__global__ __launch_bounds__(256) void penalty_kernel(
        const float* __restrict__ normals,
        const int*   __restrict__ idx8,
        float*       __restrict__ out)
{
    const int pid = blockIdx.x * BLK + threadIdx.x;   // < B*N
    const int b   = pid >> 12;
    const int* my = idx8 + (size_t)pid * KSUP;
    const float* nb_base = normals + (size_t)b * NPTS * 3;

    const int i0 = my[0];
    const float a0 = nb_base[i0*3+0], a1 = nb_base[i0*3+1], a2 = nb_base[i0*3+2];
    const float na = fmaxf(sqrtf(a0*a0 + a1*a1 + a2*a2), 1e-6f);

    float p[KSUP];
    float sum = 0.0f;
    #pragma unroll
    for (int k = 0; k < KSUP; ++k) {
        int ik = my[k];
        float b0 = nb_base[ik*3+0], b1 = nb_base[ik*3+1], b2 = nb_base[ik*3+2];
        float nbn = fmaxf(sqrtf(b0*b0 + b1*b1 + b2*b2), 1e-6f);
        float cosv = (a0*b0 + a1*b1 + a2*b2) / (na * nbn);
        p[k] = 1.0f - cosv;
        sum += p[k];
    }
    const float mean = sum * (1.0f / 8.0f);
    float var = 0.0f;
    #pragma unroll
    for (int k = 0; k < KSUP; ++k) { float dv = p[k] - mean; var += dv * dv; }
    float v = sqrtf(var * (1.0f / 7.0f)) * (1.0f / 4096.0f);

    #pragma unroll
    for (int ml = 1; ml < 64; ml <<= 1) v += __shfl_xor(v, ml, 64);
    __shared__ float red[4];
    if ((threadIdx.x & 63) == 0) red[threadIdx.x >> 6] = v;
    __syncthreads();
    if (threadIdx.x == 0) {
        atomicAdd(&out[b], red[0] + red[1] + red[2] + red[3]);
    }
}

extern "C" void kernel_launch(void* const* d_in, const int* in_sizes, int n_in,
                              void* d_out, int out_size, void* d_ws, size_t ws_size,
                              hipStream_t stream) {
    const float* xyz = (const float*)d_in[0];
    float* out = (float*)d_out;

    const int B = in_sizes[0] / (NPTS * 3);   // 4
    const int total = B * NPTS;

    float4* pts4   = (float4*)d_ws;
    float* normals = (float*)((char*)d_ws + (size_t)total * sizeof(float4));
    int*   idx8    = (int*)((char*)normals + (size_t)total * 3 * sizeof(float));

    hipMemsetAsync(d_out, 0, (size_t)out_size * sizeof(float), stream);

    hipLaunchKernelGGL(pack_kernel, dim3((total + BLK - 1) / BLK), dim3(BLK), 0, stream,
                       xyz, pts4, total);
    hipLaunchKernelGGL(knn_normal_kernel, dim3(total), dim3(BLK), 0, stream,
                       pts4, normals, idx8);
    hipLaunchKernelGGL(penalty_kernel, dim3(total / BLK), dim3(BLK), 0, stream,
                       normals, idx8, out);
}

// Round 4
// 150.330 us; speedup vs baseline: 3.0304x; 1.4964x over previous
//
#include <hip/hip_runtime.h>

typedef unsigned int uint;

#define NPTS 4096
#define BLK  256
#define KNN  32
#define KSUP 8
#define NBIN 1024
#define MAXC 256
#define LINSCALE 16.0f

// ---------------- Pass 0: pack xyz -> float4 {x,y,z,|x|^2} ----------------
__global__ __launch_bounds__(256) void pack_kernel(
        const float* __restrict__ xyz, float4* __restrict__ pts4, int total)
{
    int i = blockIdx.x * BLK + threadIdx.x;
    if (i < total) {
        float x = xyz[i*3+0], y = xyz[i*3+1], z = xyz[i*3+2];
        pts4[i] = make_float4(x, y, z, x*x + y*y + z*z);
    }
}

__device__ __forceinline__ uint fkey(float d) {
    uint u = __float_as_uint(d);
    return u ^ ((u & 0x80000000u) ? 0xFFFFFFFFu : 0x80000000u);
}
__device__ __forceinline__ float key_to_d(uint k) {
    uint u = (k & 0x80000000u) ? (k ^ 0x80000000u) : ~k;
    return __uint_as_float(u);
}
__device__ __forceinline__ uint linbin(float d) {
    return (uint)fmaxf(fminf(d * LINSCALE, 1023.0f), 0.0f);
}

// wave 0: parallel crossing-bin find over 1024-bin hist (prefix scan + unique lane)
__device__ __forceinline__ void find_cross(const uint* hist, uint* s_bin, int tid) {
    if (tid < 64) {
        const uint4* h4 = (const uint4*)hist;
        uint4 h0 = h4[tid*4+0], h1 = h4[tid*4+1], h2 = h4[tid*4+2], h3 = h4[tid*4+3];
        uint s = h0.x+h0.y+h0.z+h0.w + h1.x+h1.y+h1.z+h1.w
               + h2.x+h2.y+h2.z+h2.w + h3.x+h3.y+h3.z+h3.w;
        uint t = s;
        #pragma unroll
        for (int off = 1; off < 64; off <<= 1) {
            uint u = __shfl_up(t, off, 64);
            if (tid >= off) t += u;
        }
        uint ex = t - s;                       // exclusive prefix over lanes
        if (ex < KNN && ex + s >= KNN) {       // exactly one crossing lane
            uint cum = ex, binoff = 0;
            cum += h0.x; binoff += (cum < KNN); cum += h0.y; binoff += (cum < KNN);
            cum += h0.z; binoff += (cum < KNN); cum += h0.w; binoff += (cum < KNN);
            cum += h1.x; binoff += (cum < KNN); cum += h1.y; binoff += (cum < KNN);
            cum += h1.z; binoff += (cum < KNN); cum += h1.w; binoff += (cum < KNN);
            cum += h2.x; binoff += (cum < KNN); cum += h2.y; binoff += (cum < KNN);
            cum += h2.z; binoff += (cum < KNN); cum += h2.w; binoff += (cum < KNN);
            cum += h3.x; binoff += (cum < KNN); cum += h3.y; binoff += (cum < KNN);
            cum += h3.z; binoff += (cum < KNN); cum += h3.w; binoff += (cum < KNN);
            *s_bin = tid * 16u + binoff;
        }
    }
}

// ---------------- Pass 1: exact kNN + covariance per point ----------------
__global__ __launch_bounds__(256) void knn_cov_kernel(
        const float4* __restrict__ pts4,  // [B][N] {x,y,z,sq}
        float* __restrict__ covS,         // [B*N][12]: cov6, S3, pad
        int*   __restrict__ idx8)         // [B*N][8]
{
    const int pid = blockIdx.x;           // b*N + n
    const int b   = pid >> 12;
    const int n   = pid & (NPTS - 1);
    const int tid = threadIdx.x;
    const float4* P = pts4 + (size_t)b * NPTS;

    __shared__ uint keys[NPTS];           // 16 KB
    __shared__ uint hist[NBIN];           // 4 KB
    __shared__ uint s_bin;
    __shared__ uint s_mode;
    __shared__ uint coll_cnt;
    __shared__ uint ckey[MAXC];
    __shared__ int  cidx[MAXC];
    __shared__ int  sel[KNN];

    const float4 q = P[n];
    const float qx = q.x, qy = q.y, qz = q.z, sqn = q.w;

    #pragma unroll
    for (int i = 0; i < NBIN / BLK; ++i) hist[tid + i * BLK] = 0;
    if (tid == 0) { coll_cnt = 0; s_mode = 0; }
    __syncthreads();

    // ---- single distance pass: store keys + linear histogram ----
    #pragma unroll 4
    for (int m = tid; m < NPTS; m += BLK) {
        float4 p = P[m];
        float d = sqn + p.w - 2.0f * (qx * p.x + qy * p.y + qz * p.z);
        keys[m] = fkey(d);
        atomicAdd(&hist[linbin(d)], 1u);
    }
    __syncthreads();

    find_cross(hist, &s_bin, tid);
    __syncthreads();
    if (tid == 0 && s_bin == 1023u) s_mode = 1u;  // clamp-bin crossing: fall back
    __syncthreads();

    if (s_mode) {  // exact fallback: exponent binning (round-3 semantics)
        #pragma unroll
        for (int i = 0; i < NBIN / BLK; ++i) hist[tid + i * BLK] = 0;
        __syncthreads();
        for (int m = tid; m < NPTS; m += BLK) atomicAdd(&hist[keys[m] >> 22], 1u);
        __syncthreads();
        find_cross(hist, &s_bin, tid);
        __syncthreads();
    }
    const uint bmax = s_bin;
    const uint mode = s_mode;

    // ---- collect candidates with bin <= bmax (superset of true top-32) ----
    for (int m = tid; m < NPTS; m += BLK) {
        uint k = keys[m];
        uint bin = mode ? (k >> 22) : linbin(key_to_d(k));
        if (bin <= bmax) {
            uint pos = atomicAdd(&coll_cnt, 1u);
            if (pos < MAXC) { ckey[pos] = k; cidx[pos] = m; }
        }
    }
    __syncthreads();
    const int M = (int)min(coll_cnt, (uint)MAXC);

    // ---- exact stable rank selection (key asc, index asc) -> sel[0..31] ----
    for (int i = tid; i < M; i += BLK) {
        uint uk = ckey[i]; int ui = cidx[i];
        int r = 0;
        for (int j = 0; j < M; ++j) {
            uint vk = ckey[j];
            r += (vk < uk || (vk == uk && cidx[j] < ui)) ? 1 : 0;
        }
        if (r < KNN) sel[r] = ui;
    }
    __syncthreads();

    // ---- lanes 0..31: gather neighbors, mean, covariance ----
    if (tid < 32) {
        int j = sel[tid];
        float4 pj = P[j];
        float q0 = pj.x, q1 = pj.y, q2 = pj.z;

        float s0 = q0, s1 = q1, s2 = q2;
        #pragma unroll
        for (int ml = 1; ml < 32; ml <<= 1) {
            s0 += __shfl_xor(s0, ml, 32);
            s1 += __shfl_xor(s1, ml, 32);
            s2 += __shfl_xor(s2, ml, 32);
        }
        const float c0 = s0 * (1.0f/32.0f), c1 = s1 * (1.0f/32.0f), c2 = s2 * (1.0f/32.0f);
        const float X0 = q0 - c0, X1 = q1 - c1, X2 = q2 - c2;
        float xx = X0*X0, xy = X0*X1, xz = X0*X2, yy = X1*X1, yz = X1*X2, zz = X2*X2;
        #pragma unroll
        for (int ml = 1; ml < 32; ml <<= 1) {
            xx += __shfl_xor(xx, ml, 32);
            xy += __shfl_xor(xy, ml, 32);
            xz += __shfl_xor(xz, ml, 32);
            yy += __shfl_xor(yy, ml, 32);
            yz += __shfl_xor(yz, ml, 32);
            zz += __shfl_xor(zz, ml, 32);
        }
        if (tid == 0) {
            float4* o = (float4*)(covS + (size_t)pid * 12);
            o[0] = make_float4(xx, xy, xz, yy);
            o[1] = make_float4(yz, zz, s0 - 32.0f*qx, s1 - 32.0f*qy);
            o[2] = make_float4(s2 - 32.0f*qz, 0.0f, 0.0f, 0.0f);
        }
    }
    if (tid < KSUP) idx8[(size_t)pid*KSUP + tid] = sel[tid];
}

// ---------------- Pass 1b: per-thread 3x3 eigensolve -> oriented normal ----------------
__global__ __launch_bounds__(256) void eig_kernel(
        const float* __restrict__ covS, float* __restrict__ normals, int total)
{
    const int pid = blockIdx.x * BLK + threadIdx.x;
    if (pid >= total) return;
    const float4* c4 = (const float4*)(covS + (size_t)pid * 12);
    const float4 a = c4[0], bb = c4[1], cc = c4[2];

    double A00 = a.x, A01 = a.y, A02 = a.z, A11 = a.w, A12 = bb.x, A22 = bb.y;
    const float S0 = bb.z, S1 = bb.w, S2 = cc.x;
    double V00=1, V01=0, V02=0, V10=0, V11=1, V12=0, V20=0, V21=0, V22=1;

    #pragma unroll
    for (int sweep = 0; sweep < 5; ++sweep) {
        {
            double apq = A01;
            if (fabs(apq) > 1e-300) {
                double th = (A11 - A00) / (2.0*apq);
                double t  = (th >= 0.0 ? 1.0 : -1.0) / (fabs(th) + sqrt(th*th + 1.0));
                double c  = 1.0/sqrt(t*t + 1.0), s = t*c;
                double a00 = c*c*A00 - 2.0*s*c*A01 + s*s*A11;
                double a11 = s*s*A00 + 2.0*s*c*A01 + c*c*A11;
                double a02 = c*A02 - s*A12;
                double a12 = s*A02 + c*A12;
                A00 = a00; A11 = a11; A01 = 0.0; A02 = a02; A12 = a12;
                double v0, v1;
                v0 = V00; v1 = V01; V00 = c*v0 - s*v1; V01 = s*v0 + c*v1;
                v0 = V10; v1 = V11; V10 = c*v0 - s*v1; V11 = s*v0 + c*v1;
                v0 = V20; v1 = V21; V20 = c*v0 - s*v1; V21 = s*v0 + c*v1;
            }
        }
        {
            double apq = A02;
            if (fabs(apq) > 1e-300) {
                double th = (A22 - A00) / (2.0*apq);
                double t  = (th >= 0.0 ? 1.0 : -1.0) / (fabs(th) + sqrt(th*th + 1.0));
                double c  = 1.0/sqrt(t*t + 1.0), s = t*c;
                double a00 = c*c*A00 - 2.0*s*c*A02 + s*s*A22;
                double a22 = s*s*A00 + 2.0*s*c*A02 + c*c*A22;
                double a01 = c*A01 - s*A12;
                double a12 = s*A01 + c*A12;
                A00 = a00; A22 = a22; A02 = 0.0; A01 = a01; A12 = a12;
                double v0, v1;
                v0 = V00; v1 = V02; V00 = c*v0 - s*v1; V02 = s*v0 + c*v1;
                v0 = V10; v1 = V12; V10 = c*v0 - s*v1; V12 = s*v0 + c*v1;
                v0 = V20; v1 = V22; V20 = c*v0 - s*v1; V22 = s*v0 + c*v1;
            }
        }
        {
            double apq = A12;
            if (fabs(apq) > 1e-300) {
                double th = (A22 - A11) / (2.0*apq);
                double t  = (th >= 0.0 ? 1.0 : -1.0) / (fabs(th) + sqrt(th*th + 1.0));
                double c  = 1.0/sqrt(t*t + 1.0), s = t*c;
                double a11 = c*c*A11 - 2.0*s*c*A12 + s*s*A22;
                double a22 = s*s*A11 + 2.0*s*c*A12 + c*c*A22;
                double a01 = c*A01 - s*A02;
                double a02 = s*A01 + c*A02;
                A11 = a11; A22 = a22; A12 = 0.0; A01 = a01; A02 = a02;
                double v0, v1;
                v0 = V01; v1 = V02; V01 = c*v0 - s*v1; V02 = s*v0 + c*v1;
                v0 = V11; v1 = V12; V11 = c*v0 - s*v1; V12 = s*v0 + c*v1;
                v0 = V21; v1 = V22; V21 = c*v0 - s*v1; V22 = s*v0 + c*v1;
            }
        }
    }

    double e0 = A00, e1 = A11, e2 = A22;
    double v0, v1, v2;
    if (e0 <= e1 && e0 <= e2)      { v0 = V00; v1 = V10; v2 = V20; }
    else if (e1 <= e0 && e1 <= e2) { v0 = V01; v1 = V11; v2 = V21; }
    else                           { v0 = V02; v1 = V12; v2 = V22; }
    double nrm = sqrt(v0*v0 + v1*v1 + v2*v2);
    if (nrm > 0.0) { v0 /= nrm; v1 /= nrm; v2 /= nrm; }

    float f0 = (float)v0, f1 = (float)v1, f2 = (float)v2;
    float proj = f0*S0 + f1*S1 + f2*S2;
    if (proj < 0.0f) { f0 = -f0; f1 = -f1; f2 = -f2; }
    normals[(size_t)pid*3+0] = f0;
    normals[(size_t)pid*3+1] = f1;
    normals[(size_t)pid*3+2] = f2;
}

// ---------------- Pass 2: penalty std + batch mean ----------------
__global__ __launch_bounds__(256) void penalty_kernel(
        const float* __restrict__ normals,
        const int*   __restrict__ idx8,
        float*       __restrict__ out)
{
    const int pid = blockIdx.x * BLK + threadIdx.x;   // < B*N
    const int b   = pid >> 12;
    const int* my = idx8 + (size_t)pid * KSUP;
    const float* nb_base = normals + (size_t)b * NPTS * 3;

    const int i0 = my[0];
    const float a0 = nb_base[i0*3+0], a1 = nb_base[i0*3+1], a2 = nb_base[i0*3+2];
    const float na = fmaxf(sqrtf(a0*a0 + a1*a1 + a2*a2), 1e-6f);

    float p[KSUP];
    float sum = 0.0f;
    #pragma unroll
    for (int k = 0; k < KSUP; ++k) {
        int ik = my[k];
        float b0 = nb_base[ik*3+0], b1 = nb_base[ik*3+1], b2 = nb_base[ik*3+2];
        float nbn = fmaxf(sqrtf(b0*b0 + b1*b1 + b2*b2), 1e-6f);
        float cosv = (a0*b0 + a1*b1 + a2*b2) / (na * nbn);
        p[k] = 1.0f - cosv;
        sum += p[k];
    }
    const float mean = sum * (1.0f / 8.0f);
    float var = 0.0f;
    #pragma unroll
    for (int k = 0; k < KSUP; ++k) { float dv = p[k] - mean; var += dv * dv; }
    float v = sqrtf(var * (1.0f / 7.0f)) * (1.0f / 4096.0f);

    #pragma unroll
    for (int ml = 1; ml < 64; ml <<= 1) v += __shfl_xor(v, ml, 64);
    __shared__ float red[4];
    if ((threadIdx.x & 63) == 0) red[threadIdx.x >> 6] = v;
    __syncthreads();
    if (threadIdx.x == 0) {
        atomicAdd(&out[b], red[0] + red[1] + red[2] + red[3]);
    }
}

extern "C" void kernel_launch(void* const* d_in, const int* in_sizes, int n_in,
                              void* d_out, int out_size, void* d_ws, size_t ws_size,
                              hipStream_t stream) {
    const float* xyz = (const float*)d_in[0];
    float* out = (float*)d_out;

    const int B = in_sizes[0] / (NPTS * 3);   // 4
    const int total = B * NPTS;

    char* ws = (char*)d_ws;
    float4* pts4   = (float4*)ws;                       ws += (size_t)total * sizeof(float4);
    float*  covS   = (float*)ws;                        ws += (size_t)total * 12 * sizeof(float);
    float*  normals= (float*)ws;                        ws += (size_t)total * 3 * sizeof(float);
    int*    idx8   = (int*)ws;

    hipMemsetAsync(d_out, 0, (size_t)out_size * sizeof(float), stream);

    hipLaunchKernelGGL(pack_kernel, dim3((total + BLK - 1) / BLK), dim3(BLK), 0, stream,
                       xyz, pts4, total);
    hipLaunchKernelGGL(knn_cov_kernel, dim3(total), dim3(BLK), 0, stream,
                       pts4, covS, idx8);
    hipLaunchKernelGGL(eig_kernel, dim3((total + BLK - 1) / BLK), dim3(BLK), 0, stream,
                       covS, normals, total);
    hipLaunchKernelGGL(penalty_kernel, dim3(total / BLK), dim3(BLK), 0, stream,
                       normals, idx8, out);
}